// Round 1
// baseline (288.294 us; speedup 1.0000x reference)
//
#include <hip/hip_runtime.h>
#include <hip/hip_bf16.h>

#define SEQ   64
#define BATCH 8192
#define OBS   47
#define HID   64
#define G4    256
#define MLPH  32
#define ACT   12

#define BT    32      // batch rows per workgroup
#define NT    512     // threads per workgroup (8 waves)
#define WCT_S 136     // K-stride (shorts) for weight / A tiles (128 + 8 pad)
#define GL_S  257     // gates LDS stride (floats)
#define M1_S  33      // mlp1 LDS stride (floats)
#define M2_S  40      // elu-out LDS stride (shorts)
#define W1_S  72      // W1T LDS stride (shorts)
#define W2_S  40      // W2T LDS stride (shorts)

#define LDS_BYTES 125120

typedef __attribute__((ext_vector_type(8))) short short8;
typedef __attribute__((ext_vector_type(4))) float f32x4;

__device__ __forceinline__ ushort f2bf(float f) {
  union { float f; unsigned u; } v; v.f = f;
  return (ushort)((v.u + 0x7FFFu + ((v.u >> 16) & 1u)) >> 16);
}
__device__ __forceinline__ float sigf(float x) { return 1.0f / (1.0f + __expf(-x)); }
__device__ __forceinline__ float tanhfast(float x) { return 1.0f - 2.0f / (1.0f + __expf(2.0f * x)); }

extern "C" __global__ void __launch_bounds__(NT, 1)
lstm_policy(const float* __restrict__ obs, const float* __restrict__ h0,
            const float* __restrict__ c0, const float* __restrict__ Wih,
            const float* __restrict__ Whh, const float* __restrict__ bih,
            const float* __restrict__ bhh, const float* __restrict__ W1,
            const float* __restrict__ b1, const float* __restrict__ W2,
            const float* __restrict__ b2, const int* __restrict__ masks,
            float* __restrict__ out)
{
  extern __shared__ __align__(16) char smem[];
  float*  glds = (float*)smem;            // 32*257 fp32 = 32896 B
  float*  m1   = glds + BT * GL_S;        // 32*33        =  4224 B
  float*  bias = m1 + BT * M1_S;          // 256          =  1024 B
  float*  b1s  = bias + G4;               // 32           =   128 B
  float*  b2s  = b1s + MLPH;              // 16           =    64 B
  ushort* WcT  = (ushort*)(b2s + 16);     // 256*136 bf16 = 69632 B
  ushort* As   = WcT + G4 * WCT_S;        // 32*136       =  8704 B
  ushort* W1T  = As + BT * WCT_S;         // 32*72        =  4608 B
  ushort* W2T  = W1T + MLPH * W1_S;       // 16*40        =  1280 B
  ushort* m2a  = W2T + 16 * W2_S;         // 32*40        =  2560 B   total 125120

  const int tid  = threadIdx.x;
  const int b0   = blockIdx.x * BT;
  const int lane = tid & 63, wave = tid >> 6;
  const int lr   = lane & 15, lg = lane >> 4;

  // ---------- one-time staging ----------
  // Combined weights, transposed: WcT[n][k], k<47 -> W_ih, 64<=k<128 -> W_hh, else 0
  for (int idx = tid; idx < G4 * WCT_S; idx += NT) {
    int n = idx / WCT_S, k = idx - n * WCT_S;
    float v = 0.f;
    if (k < OBS) v = Wih[n * OBS + k];
    else if (k >= 64 && k < 128) v = Whh[n * 64 + (k - 64)];
    WcT[idx] = f2bf(v);
  }
  for (int idx = tid; idx < BT * WCT_S; idx += NT) As[idx] = 0;   // zero pads
  for (int idx = tid; idx < MLPH * W1_S; idx += NT) {
    int n = idx / W1_S, k = idx - n * W1_S;
    W1T[idx] = f2bf(k < HID ? W1[n * HID + k] : 0.f);
  }
  for (int idx = tid; idx < 16 * W2_S; idx += NT) {
    int n = idx / W2_S, k = idx - n * W2_S;
    W2T[idx] = f2bf((n < ACT && k < MLPH) ? W2[n * MLPH + k] : 0.f);
  }
  for (int n = tid; n < G4; n += NT) bias[n] = bih[n] + bhh[n];
  if (tid < MLPH) b1s[tid] = b1[tid];
  if (tid < 16)   b2s[tid] = (tid < ACT) ? b2[tid] : 0.f;
  __syncthreads();   // fence: As zeroing vs per-thread h writes below

  // fixed thread -> (batch-row, hidden) map: j = lane-ish, 4 rows per thread
  const int j  = tid & 63;
  const int bq = (tid >> 6) * 4;
  float hreg[4], creg[4];
  for (int q = 0; q < 4; ++q) {
    int bp = bq + q;
    hreg[q] = h0[(b0 + bp) * HID + j];
    creg[q] = c0[(b0 + bp) * HID + j];
    As[bp * WCT_S + 64 + j] = f2bf(hreg[q]);
  }

  for (int t = 0; t < SEQ; ++t) {
    // ---- Phase A: mask reset + stage x(t) into A ----
    for (int q = 0; q < 4; ++q) {
      int bp = bq + q;
      int m = masks[t * BATCH + b0 + bp];
      if (m == 0) {
        hreg[q] = 0.f; creg[q] = 0.f;
        As[bp * WCT_S + 64 + j] = 0;
      }
    }
    {
      int base = (t * BATCH + b0) * OBS;   // rows of this tile are contiguous
      for (int idx = tid; idx < BT * OBS; idx += NT) {
        int r = idx / OBS, k = idx - r * OBS;
        As[r * WCT_S + k] = f2bf(obs[base + idx]);
      }
    }
    __syncthreads();

    // ---- Phase B: gates = [x|h] @ Wc + b  (all 8 waves, 16 MFMA each) ----
    {
      int mrow = (wave >> 2) * 16;
      int ncol = (wave & 3) * 64;
      f32x4 acc[4];
      #pragma unroll
      for (int nf = 0; nf < 4; ++nf) {
        float bz = bias[ncol + nf * 16 + lr];
        f32x4 tmp = {bz, bz, bz, bz};
        acc[nf] = tmp;
      }
      #pragma unroll
      for (int kk = 0; kk < 4; ++kk) {
        int k0 = kk * 32 + lg * 8;
        short8 af = *(const short8*)(As + (mrow + lr) * WCT_S + k0);
        #pragma unroll
        for (int nf = 0; nf < 4; ++nf) {
          short8 bf = *(const short8*)(WcT + (ncol + nf * 16 + lr) * WCT_S + k0);
          acc[nf] = __builtin_amdgcn_mfma_f32_16x16x32_bf16(af, bf, acc[nf], 0, 0, 0);
        }
      }
      #pragma unroll
      for (int nf = 0; nf < 4; ++nf)
        #pragma unroll
        for (int r = 0; r < 4; ++r)
          glds[(mrow + lg * 4 + r) * GL_S + ncol + nf * 16 + lr] = acc[nf][r];
    }
    __syncthreads();

    // ---- Phase C: LSTM cell update (fp32), write h as bf16 into A ----
    for (int q = 0; q < 4; ++q) {
      int bp = bq + q;
      const float* gb = glds + bp * GL_S + j;
      float gi = gb[0], gf = gb[64], gg = gb[128], go = gb[192];
      float iv = sigf(gi), fv = sigf(gf), gv = tanhfast(gg), ov = sigf(go);
      float c = fv * creg[q] + iv * gv;
      float h = ov * tanhfast(c);
      creg[q] = c; hreg[q] = h;
      As[bp * WCT_S + 64 + j] = f2bf(h);
    }
    __syncthreads();

    // ---- Phase D: MLP layer 1 (h @ W1T + b1), waves 0-3 ----
    if (wave < 4) {
      int mrow = (wave >> 1) * 16;
      int ncol = (wave & 1) * 16;
      float bz = b1s[ncol + lr];
      f32x4 acc = {bz, bz, bz, bz};
      #pragma unroll
      for (int kk = 0; kk < 2; ++kk) {
        int k0 = kk * 32 + lg * 8;
        short8 af = *(const short8*)(As + (mrow + lr) * WCT_S + 64 + k0);
        short8 bf = *(const short8*)(W1T + (ncol + lr) * W1_S + k0);
        acc = __builtin_amdgcn_mfma_f32_16x16x32_bf16(af, bf, acc, 0, 0, 0);
      }
      #pragma unroll
      for (int r = 0; r < 4; ++r)
        m1[(mrow + lg * 4 + r) * M1_S + ncol + lr] = acc[r];
    }
    __syncthreads();

    // ---- Phase E: ELU -> bf16 ----
    for (int idx = tid; idx < BT * MLPH; idx += NT) {
      int r = idx >> 5, cc = idx & 31;
      float v = m1[r * M1_S + cc];
      float e = v > 0.f ? v : (__expf(v) - 1.f);
      m2a[r * M2_S + cc] = f2bf(e);
    }
    __syncthreads();

    // ---- Phase F: MLP layer 2 (+b2) and store means, waves 0-1 ----
    if (wave < 2) {
      int mrow = wave * 16;
      float bz = b2s[lr];
      f32x4 acc = {bz, bz, bz, bz};
      int k0 = lg * 8;
      short8 af = *(const short8*)(m2a + (mrow + lr) * M2_S + k0);
      short8 bf = *(const short8*)(W2T + lr * W2_S + k0);
      acc = __builtin_amdgcn_mfma_f32_16x16x32_bf16(af, bf, acc, 0, 0, 0);
      if (lr < ACT) {
        #pragma unroll
        for (int r = 0; r < 4; ++r) {
          int brow = b0 + mrow + lg * 4 + r;
          out[(t * BATCH + brow) * ACT + lr] = acc[r];
        }
      }
    }
    // no barrier needed: next-iter Phase A touches only As (not m2a/W2T),
    // and everyone re-syncs at Phase A's barrier.
  }

  // ---- final h, c ----
  {
    float* hout = out + SEQ * BATCH * ACT;
    float* cout = hout + BATCH * HID;
    for (int q = 0; q < 4; ++q) {
      int bp = bq + q;
      hout[(b0 + bp) * HID + j] = hreg[q];
      cout[(b0 + bp) * HID + j] = creg[q];
    }
  }
}

extern "C" void kernel_launch(void* const* d_in, const int* in_sizes, int n_in,
                              void* d_out, int out_size, void* d_ws, size_t ws_size,
                              hipStream_t stream) {
  (void)in_sizes; (void)n_in; (void)d_ws; (void)ws_size; (void)out_size;
  // dynamic LDS > 64KB opt-in (idempotent; not a stream op -> capture-safe)
  hipFuncSetAttribute(reinterpret_cast<const void*>(lstm_policy),
                      hipFuncAttributeMaxDynamicSharedMemorySize, LDS_BYTES);
  lstm_policy<<<dim3(BATCH / BT), dim3(NT), LDS_BYTES, stream>>>(
      (const float*)d_in[0], (const float*)d_in[1], (const float*)d_in[2],
      (const float*)d_in[3], (const float*)d_in[4], (const float*)d_in[5],
      (const float*)d_in[6], (const float*)d_in[7], (const float*)d_in[8],
      (const float*)d_in[9], (const float*)d_in[10], (const int*)d_in[11],
      (float*)d_out);
}

// Round 3
// 183.532 us; speedup vs baseline: 1.5708x; 1.5708x over previous
//
#include <hip/hip_runtime.h>
#include <hip/hip_bf16.h>

#define SEQ   64
#define BATCH 8192
#define OBS   47
#define HID   64
#define MLPH  32
#define ACT   12

#define BT 16            // batch rows per workgroup
#define NT 256           // 4 waves
#define NWG (BATCH / BT) // 512 workgroups -> 2 per CU

// steady-state LDS byte offsets (overlaid on the 64KB setup WcT region)
#define XS_OFF 0         // x tile [16][64] bf16 swizzled (k 0..46 + pad)   2048 B
#define HB_OFF 2048      // hbuf[2][16][64] bf16 swizzled (ping-pong)       4096 B
#define HM_OFF 6144      // hm  [16][64] bf16 (unmasked h for MLP)          2048 B
#define M2_OFF 8192      // m2a [16][32] bf16 (elu out)                     1024 B
#define MF_OFF 9216      // maskf [65][16] f32                              4160 B
#define LDS_BYTES 65536  // setup view: WcT[256][128] bf16, swizzled

typedef __attribute__((ext_vector_type(8))) short short8;
typedef __attribute__((ext_vector_type(4))) float f32x4;

__device__ __forceinline__ ushort f2bf(float f) {
  union { float f; unsigned u; } v; v.f = f;
  return (ushort)((v.u + 0x7FFFu + ((v.u >> 16) & 1u)) >> 16);
}
__device__ __forceinline__ float sigf(float x) { return 1.0f / (1.0f + __expf(-x)); }
__device__ __forceinline__ float tanhfast(float x) { return 1.0f - 2.0f / (1.0f + __expf(2.0f * x)); }

// swizzle: XOR row-low-bits into the 16B-slot bits (bijective within a row set)
__device__ __forceinline__ int swzA(int r, int kshort)  { return (r * 256 + kshort * 2) ^ ((r & 7) << 4); }  // stride 256B (setup WcT)
__device__ __forceinline__ int swzH(int r, int kshort)  { return (r * 128 + kshort * 2) ^ ((r & 7) << 4); }  // stride 128B
__device__ __forceinline__ int swzM(int r, int cshort)  { return (r * 64  + cshort * 2) ^ ((r & 7) << 4); }  // stride 64B

extern "C" __global__ void __launch_bounds__(NT, 2)
lstm_policy(const float* __restrict__ obs, const float* __restrict__ h0,
            const float* __restrict__ c0, const float* __restrict__ Wih,
            const float* __restrict__ Whh, const float* __restrict__ bih,
            const float* __restrict__ bhh, const float* __restrict__ W1,
            const float* __restrict__ b1, const float* __restrict__ W2,
            const float* __restrict__ b2, const int* __restrict__ masks,
            float* __restrict__ out)
{
  extern __shared__ __align__(16) char smem[];
  const int tid = threadIdx.x;
  const int b0  = blockIdx.x * BT;
  const int lane = tid & 63;
  const int w  = tid >> 6;     // wave 0..3
  const int lr = lane & 15;
  const int lg = lane >> 4;    // 0..3
  const int j  = w * 16 + lr;  // hidden unit owned by this lane

  // ---------------- setup: stage gate-interleaved Wc^T into LDS ----------------
  // logical col p = w*64 + nf*16 + lr  <->  gate-matrix row n = nf*64 + w*16 + lr
  for (int idx = tid; idx < 256 * 128; idx += NT) {
    int p = idx >> 7, k = idx & 127;
    int pw = p >> 6, pnf = (p >> 4) & 3, plr = p & 15;
    int n = pnf * 64 + pw * 16 + plr;
    float v = 0.f;
    if (k < OBS) v = Wih[n * OBS + k];
    else if (k >= 64) v = Whh[n * HID + (k - 64)];
    *(ushort*)(smem + swzA(p, k)) = f2bf(v);
  }
  __syncthreads();

  // gate B-fragments -> registers (step-invariant)
  short8 bg[4][4];
  #pragma unroll
  for (int nf = 0; nf < 4; ++nf) {
    int p = w * 64 + nf * 16 + lr;
    #pragma unroll
    for (int kk = 0; kk < 4; ++kk)
      bg[nf][kk] = *(const short8*)(smem + swzA(p, kk * 32 + lg * 8));
  }

  float biasg[4];
  #pragma unroll
  for (int nf = 0; nf < 4; ++nf) {
    int n = nf * 64 + j;
    biasg[nf] = bih[n] + bhh[n];
  }

  // MLP weight fragments (only wave 0 uses them; loaded uniformly)
  short8 w1f[2][2];
  #pragma unroll
  for (int tt = 0; tt < 2; ++tt)
    #pragma unroll
    for (int kk = 0; kk < 2; ++kk) {
      const float* src = W1 + (tt * 16 + lr) * HID + kk * 32 + lg * 8;
      short8 f;
      #pragma unroll
      for (int e = 0; e < 8; ++e) f[e] = (short)f2bf(src[e]);
      w1f[tt][kk] = f;
    }
  short8 w2f;
  #pragma unroll
  for (int e = 0; e < 8; ++e)
    w2f[e] = (lr < ACT) ? (short)f2bf(W2[lr * MLPH + lg * 8 + e]) : (short)0;
  float b1v[2]; b1v[0] = b1[lr]; b1v[1] = b1[16 + lr];
  float b2v = (lr < ACT) ? b2[lr] : 0.f;

  __syncthreads();   // all WcT reads done -> overlay steady buffers

  // ---------------- steady-buffer init ----------------
  for (int idx = tid; idx < SEQ * BT; idx += NT) {
    int t = idx >> 4, r = idx & 15;
    *(float*)(smem + MF_OFF + idx * 4) = (float)masks[t * BATCH + b0 + r];
  }
  if (tid < BT) *(float*)(smem + MF_OFF + (SEQ * BT + tid) * 4) = 1.0f;  // m(64)=1
  for (int idx = tid; idx < BT * 64; idx += NT)
    *(ushort*)(smem + XS_OFF + idx * 2) = 0;   // zero x tile incl. k=47..63 pads
  for (int idx = tid; idx < 2 * BT * 64; idx += NT)
    *(ushort*)(smem + HB_OFF + idx * 2) = 0;   // zero both h buffers
  __syncthreads();

  // per-lane c state + h0 into hbuf[0] (apply m(0))
  float creg[4];
  #pragma unroll
  for (int q = 0; q < 4; ++q) {
    int r = lg * 4 + q;
    float mf = *(const float*)(smem + MF_OFF + r * 4);
    float hv = h0[(b0 + r) * HID + j] * mf;
    creg[q]  = c0[(b0 + r) * HID + j] * mf;
    *(ushort*)(smem + HB_OFF + swzH(r, j)) = f2bf(hv);
  }

  // obs prefetch lane assignment: 188 lanes of waves 1-3 cover 16*47 floats
  const int oidx = tid - 64;
  const bool oact = (w > 0) && (oidx < 188);
  int a_obs[4] = {0, 0, 0, 0};
  if (oact) {
    #pragma unroll
    for (int e = 0; e < 4; ++e) {
      int flat = oidx * 4 + e;
      int r = flat / 47, k = flat - 47 * r;
      a_obs[e] = swzH(r, k);
    }
    // stage obs(0)
    const f32x4 v = *(const f32x4*)(obs + (size_t)b0 * OBS + oidx * 4);
    #pragma unroll
    for (int e = 0; e < 4; ++e)
      *(ushort*)(smem + XS_OFF + a_obs[e]) = f2bf(v[e]);
  }
  __syncthreads();   // barrier-1 for t=0: x(0) staged, h(0)*m(0) in hbuf[0]

  // ---------------- time loop: 2 barriers per step ----------------
  // gates at step t read hbuf[t&1]; cell writes h(t)*m(t+1) into hbuf[(t+1)&1]
  float hlast[4] = {0, 0, 0, 0};
  for (int t = 0; t < SEQ; ++t) {
    // issue obs(t+1) prefetch early (latency hides under gates)
    f32x4 ov = {0.f, 0.f, 0.f, 0.f};
    if (oact && t + 1 < SEQ)
      ov = *(const f32x4*)(obs + ((size_t)(t + 1) * BATCH + b0) * OBS + oidx * 4);

    const int hb_rd = HB_OFF + (t & 1) * 2048;
    const int hb_wr = HB_OFF + ((t + 1) & 1) * 2048;

    // gates MFMA: A from LDS (x tile + h buffer), B from registers; C-init = bias
    f32x4 acc[4];
    #pragma unroll
    for (int nf = 0; nf < 4; ++nf)
      acc[nf] = (f32x4){biasg[nf], biasg[nf], biasg[nf], biasg[nf]};
    #pragma unroll
    for (int kk = 0; kk < 2; ++kk) {
      short8 af = *(const short8*)(smem + XS_OFF + swzH(lr, kk * 32 + lg * 8));
      #pragma unroll
      for (int nf = 0; nf < 4; ++nf)
        acc[nf] = __builtin_amdgcn_mfma_f32_16x16x32_bf16(af, bg[nf][kk], acc[nf], 0, 0, 0);
    }
    #pragma unroll
    for (int kk = 0; kk < 2; ++kk) {
      short8 af = *(const short8*)(smem + hb_rd + swzH(lr, kk * 32 + lg * 8));
      #pragma unroll
      for (int nf = 0; nf < 4; ++nf)
        acc[nf] = __builtin_amdgcn_mfma_f32_16x16x32_bf16(af, bg[nf][kk + 2], acc[nf], 0, 0, 0);
    }

    float mnext[4];
    #pragma unroll
    for (int q = 0; q < 4; ++q)
      mnext[q] = *(const float*)(smem + MF_OFF + ((t + 1) * BT + lg * 4 + q) * 4);

    // LSTM cell entirely in registers (gate-interleaved layout: acc[gate][row])
    #pragma unroll
    for (int q = 0; q < 4; ++q) {
      int r = lg * 4 + q;
      float iv = sigf(acc[0][q]);
      float fv = sigf(acc[1][q]);
      float gv = tanhfast(acc[2][q]);
      float o  = sigf(acc[3][q]);
      float c  = fv * creg[q] + iv * gv;
      float h  = o * tanhfast(c);
      hlast[q] = h;
      creg[q]  = c * mnext[q];                                    // mask lookahead
      *(ushort*)(smem + hb_wr + swzH(r, j)) = f2bf(h * mnext[q]); // no race: other buffer
      *(ushort*)(smem + HM_OFF + swzH(r, j)) = f2bf(h);           // unmasked, for MLP
    }
    __syncthreads();   // barrier-2: h staged; all gates reads of x/hbuf complete

    if (w == 0) {
      // ---- entire MLP in one wave: no extra barriers ----
      f32x4 am0 = (f32x4){b1v[0], b1v[0], b1v[0], b1v[0]};
      f32x4 am1 = (f32x4){b1v[1], b1v[1], b1v[1], b1v[1]};
      #pragma unroll
      for (int kk = 0; kk < 2; ++kk) {
        short8 hf = *(const short8*)(smem + HM_OFF + swzH(lr, kk * 32 + lg * 8));
        am0 = __builtin_amdgcn_mfma_f32_16x16x32_bf16(hf, w1f[0][kk], am0, 0, 0, 0);
        am1 = __builtin_amdgcn_mfma_f32_16x16x32_bf16(hf, w1f[1][kk], am1, 0, 0, 0);
      }
      #pragma unroll
      for (int q = 0; q < 4; ++q) {
        int r = lg * 4 + q;
        float v0 = am0[q], v1 = am1[q];
        float e0 = v0 > 0.f ? v0 : (__expf(v0) - 1.f);
        float e1 = v1 > 0.f ? v1 : (__expf(v1) - 1.f);
        *(ushort*)(smem + M2_OFF + swzM(r, lr))      = f2bf(e0);
        *(ushort*)(smem + M2_OFF + swzM(r, 16 + lr)) = f2bf(e1);
      }
      // same-wave LDS RAW: compiler inserts lgkmcnt wait before the read
      f32x4 a2 = (f32x4){b2v, b2v, b2v, b2v};
      {
        short8 ef = *(const short8*)(smem + M2_OFF + swzM(lr, lg * 8));
        a2 = __builtin_amdgcn_mfma_f32_16x16x32_bf16(ef, w2f, a2, 0, 0, 0);
      }
      if (lr < ACT) {
        #pragma unroll
        for (int q = 0; q < 4; ++q) {
          int r = lg * 4 + q;
          out[((size_t)t * BATCH + b0 + r) * ACT + lr] = a2[q];
        }
      }
    } else if (oact && t + 1 < SEQ) {
      // waves 1-3: commit prefetched obs(t+1) into the x tile
      #pragma unroll
      for (int e = 0; e < 4; ++e)
        *(ushort*)(smem + XS_OFF + a_obs[e]) = f2bf(ov[e]);
    }
    __syncthreads();   // barrier-1 for t+1
  }

  // ---------------- final h, c ----------------
  float* hout = out + (size_t)SEQ * BATCH * ACT;
  float* cout = hout + (size_t)BATCH * HID;
  #pragma unroll
  for (int q = 0; q < 4; ++q) {
    int r = lg * 4 + q;
    hout[(size_t)(b0 + r) * HID + j] = hlast[q];   // h(63) unmasked
    cout[(size_t)(b0 + r) * HID + j] = creg[q];    // c(63) * m(64)=1
  }
}

extern "C" void kernel_launch(void* const* d_in, const int* in_sizes, int n_in,
                              void* d_out, int out_size, void* d_ws, size_t ws_size,
                              hipStream_t stream) {
  (void)in_sizes; (void)n_in; (void)d_ws; (void)ws_size; (void)out_size;
  hipFuncSetAttribute(reinterpret_cast<const void*>(lstm_policy),
                      hipFuncAttributeMaxDynamicSharedMemorySize, LDS_BYTES);
  lstm_policy<<<dim3(NWG), dim3(NT), LDS_BYTES, stream>>>(
      (const float*)d_in[0], (const float*)d_in[1], (const float*)d_in[2],
      (const float*)d_in[3], (const float*)d_in[4], (const float*)d_in[5],
      (const float*)d_in[6], (const float*)d_in[7], (const float*)d_in[8],
      (const float*)d_in[9], (const float*)d_in[10], (const int*)d_in[11],
      (float*)d_out);
}

// Round 4
// 153.442 us; speedup vs baseline: 1.8789x; 1.1961x over previous
//
#include <hip/hip_runtime.h>
#include <hip/hip_bf16.h>

#define SEQ   64
#define BATCH 8192
#define OBS   47
#define HID   64
#define MLPH  32
#define ACT   12

#define BT 16            // batch rows per workgroup
#define NT 512           // 8 waves: 0-3 gates+cell, 4 MLP, 5-7 obs staging
#define NWG (BATCH / BT) // 512 workgroups -> 2 per CU, 16 waves/CU

// LDS layout (bytes). x/hb/hm are [16][64] bf16 swizzled, 2048 B each.
#define XS0 0
#define XS1 2048
#define HB0 4096
#define HB1 6144
#define HM0 8192
#define HM1 10240
#define M2O 12288        // [16][32] bf16 swizzled, 1024 B (wave-4 local)
#define MSK 13312        // [65][16] f32, 4160 B
#define W1L 17472        // 4 frags x 64 lanes x 16 B = 4096 B
#define W2L 21568        // 64 lanes x 16 B = 1024 B
#define SMEM_BYTES 22592

typedef __attribute__((ext_vector_type(8))) short short8;
typedef __attribute__((ext_vector_type(4))) float f32x4;

__device__ __forceinline__ ushort f2bf(float f) {
  union { float f; unsigned u; } v; v.f = f;
  return (ushort)((v.u + 0x7FFFu + ((v.u >> 16) & 1u)) >> 16);
}
__device__ __forceinline__ float sigf(float x) { return 1.0f / (1.0f + __expf(-x)); }
__device__ __forceinline__ float tanhfast(float x) { return 1.0f - 2.0f / (1.0f + __expf(2.0f * x)); }

// XOR swizzles (bijective: row bits folded into the 16B-slot bits)
__device__ __forceinline__ int swz (int r, int ks) { return (r * 128 + ks * 2) ^ ((r & 7) << 4); }
__device__ __forceinline__ int swzM(int r, int cs) { return (r * 64  + cs * 2) ^ ((r & 7) << 4); }

extern "C" __global__ void __launch_bounds__(NT, 4)
lstm_policy(const float* __restrict__ obs, const float* __restrict__ h0,
            const float* __restrict__ c0, const float* __restrict__ Wih,
            const float* __restrict__ Whh, const float* __restrict__ bih,
            const float* __restrict__ bhh, const float* __restrict__ W1,
            const float* __restrict__ b1, const float* __restrict__ W2,
            const float* __restrict__ b2, const int* __restrict__ masks,
            float* __restrict__ out)
{
  __shared__ __align__(16) char sm[SMEM_BYTES];
  const int tid  = threadIdx.x;
  const int b0   = blockIdx.x * BT;
  const int lane = tid & 63;
  const int w    = tid >> 6;          // 0..7
  const int lr   = lane & 15;
  const int lg   = lane >> 4;         // 0..3
  const int j    = (w & 3) * 16 + lr; // hidden unit owned (heavy waves)

  int myAfrag[2];
  myAfrag[0] = swz(lr, lg * 8);
  myAfrag[1] = swz(lr, 32 + lg * 8);

  // ---------------- setup: zero x/hb/hm, stage masks + MLP weight frags ----------------
  for (int idx = tid; idx < 768; idx += NT)          // 12288 B = XS0..HM1
    *(f32x4*)(sm + idx * 16) = (f32x4){0.f, 0.f, 0.f, 0.f};

  for (int idx = tid; idx < SEQ * BT; idx += NT) {
    int t = idx >> 4, r = idx & 15;
    *(float*)(sm + MSK + idx * 4) = (float)masks[t * BATCH + b0 + r];
  }
  if (tid < BT) *(float*)(sm + MSK + (SEQ * BT + tid) * 4) = 1.0f;  // m(64)=1

  if (tid < 64) {   // MLP weight fragments, one lane-slot per thread
    int l = tid, llr = l & 15, llg = l >> 4;
    #pragma unroll
    for (int tt = 0; tt < 2; ++tt)
      #pragma unroll
      for (int kk = 0; kk < 2; ++kk) {
        short8 f;
        const float* src = W1 + (tt * 16 + llr) * HID + kk * 32 + llg * 8;
        #pragma unroll
        for (int e = 0; e < 8; ++e) f[e] = (short)f2bf(src[e]);
        *(short8*)(sm + W1L + ((tt * 2 + kk) * 64 + l) * 16) = f;
      }
    short8 f2;
    #pragma unroll
    for (int e = 0; e < 8; ++e)
      f2[e] = (llr < ACT) ? (short)f2bf(W2[llr * MLPH + llg * 8 + e]) : (short)0;
    *(short8*)(sm + W2L + l * 16) = f2;
  }

  // ---------------- heavy-wave gate weights: direct from global (k-contiguous) ----------------
  short8 bg[4][4];
  float biasg[4];
  if (w < 4) {
    #pragma unroll
    for (int nf = 0; nf < 4; ++nf) {
      int n = nf * 64 + j;           // torch gate order i,f,g,o
      biasg[nf] = bih[n] + bhh[n];
      #pragma unroll
      for (int kk = 0; kk < 2; ++kk) {   // x part: Wih row, predicated past 47
        short8 f;
        #pragma unroll
        for (int e = 0; e < 8; ++e) {
          int k = kk * 32 + lg * 8 + e;
          f[e] = (k < OBS) ? (short)f2bf(Wih[n * OBS + k]) : (short)0;
        }
        bg[nf][kk] = f;
      }
      #pragma unroll
      for (int kk = 0; kk < 2; ++kk) {   // h part: Whh row, fully in-bounds
        const float* src = Whh + n * HID + kk * 32 + lg * 8;
        short8 f;
        #pragma unroll
        for (int e = 0; e < 8; ++e) f[e] = (short)f2bf(src[e]);
        bg[nf][kk + 2] = f;
      }
    }
  }

  float b1v0 = 0.f, b1v1 = 0.f, b2v = 0.f;
  if (w == 4) { b1v0 = b1[lr]; b1v1 = b1[16 + lr]; b2v = (lr < ACT) ? b2[lr] : 0.f; }

  __syncthreads();   // LDS staging complete (incl. zeros + MSK)

  // ---------------- initial state ----------------
  float creg[4] = {0, 0, 0, 0}, hlast[4] = {0, 0, 0, 0};
  int myHwr[4] = {0, 0, 0, 0};
  if (w < 4) {
    #pragma unroll
    for (int q = 0; q < 4; ++q) {
      int r = lg * 4 + q;
      myHwr[q] = swz(r, j);
      float m0 = *(const float*)(sm + MSK + r * 4);
      float hv = h0[(size_t)(b0 + r) * HID + j] * m0;
      creg[q]  = c0[(size_t)(b0 + r) * HID + j] * m0;
      *(ushort*)(sm + HB0 + myHwr[q]) = f2bf(hv);
    }
  }

  // obs staging lanes: waves 5-7 cover 16*47 = 752 floats as 188 x f32x4
  const int oidx = tid - 320;
  const bool oact = (w >= 5) && (oidx >= 0) && (oidx < 188);
  int a_obs[4] = {0, 0, 0, 0};
  f32x4 ovh = {0.f, 0.f, 0.f, 0.f};
  if (oact) {
    #pragma unroll
    for (int e = 0; e < 4; ++e) {
      int flat = oidx * 4 + e;
      int r = flat / OBS, k = flat - OBS * r;
      a_obs[e] = swz(r, k);
    }
    f32x4 v0 = *(const f32x4*)(obs + (size_t)b0 * OBS + oidx * 4);   // obs(0)
    #pragma unroll
    for (int e = 0; e < 4; ++e) *(ushort*)(sm + XS0 + a_obs[e]) = f2bf(v0[e]);
    ovh = *(const f32x4*)(obs + ((size_t)BATCH + b0) * OBS + oidx * 4);  // prefetch obs(1)
  }
  __syncthreads();   // t=0 ready: x(0) in XS0, h(0)*m(0) in HB0

  // ---------------- MLP body (wave 4): means(TOUT) from hm buffer HMP ----------------
  auto do_mlp = [&](int TOUT, int HMP) {
    short8 hf0 = *(const short8*)(sm + HMP + myAfrag[0]);
    short8 hf1 = *(const short8*)(sm + HMP + myAfrag[1]);
    f32x4 am0 = (f32x4){b1v0, b1v0, b1v0, b1v0};
    f32x4 am1 = (f32x4){b1v1, b1v1, b1v1, b1v1};
    short8 wA;
    wA = *(const short8*)(sm + W1L + (0 * 64 + lane) * 16);
    am0 = __builtin_amdgcn_mfma_f32_16x16x32_bf16(hf0, wA, am0, 0, 0, 0);
    wA = *(const short8*)(sm + W1L + (1 * 64 + lane) * 16);
    am0 = __builtin_amdgcn_mfma_f32_16x16x32_bf16(hf1, wA, am0, 0, 0, 0);
    wA = *(const short8*)(sm + W1L + (2 * 64 + lane) * 16);
    am1 = __builtin_amdgcn_mfma_f32_16x16x32_bf16(hf0, wA, am1, 0, 0, 0);
    wA = *(const short8*)(sm + W1L + (3 * 64 + lane) * 16);
    am1 = __builtin_amdgcn_mfma_f32_16x16x32_bf16(hf1, wA, am1, 0, 0, 0);
    #pragma unroll
    for (int q = 0; q < 4; ++q) {
      int r = lg * 4 + q;
      float v0 = am0[q], v1 = am1[q];
      float e0 = v0 > 0.f ? v0 : (__expf(v0) - 1.f);
      float e1 = v1 > 0.f ? v1 : (__expf(v1) - 1.f);
      *(ushort*)(sm + M2O + swzM(r, lr))      = f2bf(e0);
      *(ushort*)(sm + M2O + swzM(r, 16 + lr)) = f2bf(e1);
    }
    // same-wave LDS RAW: ds ops complete in order w/ compiler lgkmcnt
    f32x4 a2 = (f32x4){b2v, b2v, b2v, b2v};
    short8 ef  = *(const short8*)(sm + M2O + swzM(lr, lg * 8));
    short8 w2f = *(const short8*)(sm + W2L + lane * 16);
    a2 = __builtin_amdgcn_mfma_f32_16x16x32_bf16(ef, w2f, a2, 0, 0, 0);
    if (lr < ACT) {
      #pragma unroll
      for (int q = 0; q < 4; ++q)
        out[((size_t)TOUT * BATCH + b0 + lg * 4 + q) * ACT + lr] = a2[q];
    }
  };

  // ---------------- one step: ONE barrier ----------------
  auto do_step = [&](int T, int XRD, int XWR, int HBRD, int HBWR, int HMPREV, int HMWR) {
    if (w < 4) {
      // gates = [x|h] @ Wc + b ; B-frags in registers
      f32x4 acc0 = (f32x4){biasg[0], biasg[0], biasg[0], biasg[0]};
      f32x4 acc1 = (f32x4){biasg[1], biasg[1], biasg[1], biasg[1]};
      f32x4 acc2 = (f32x4){biasg[2], biasg[2], biasg[2], biasg[2]};
      f32x4 acc3 = (f32x4){biasg[3], biasg[3], biasg[3], biasg[3]};
      short8 afx0 = *(const short8*)(sm + XRD  + myAfrag[0]);
      short8 afx1 = *(const short8*)(sm + XRD  + myAfrag[1]);
      short8 afh0 = *(const short8*)(sm + HBRD + myAfrag[0]);
      short8 afh1 = *(const short8*)(sm + HBRD + myAfrag[1]);
      acc0 = __builtin_amdgcn_mfma_f32_16x16x32_bf16(afx0, bg[0][0], acc0, 0, 0, 0);
      acc1 = __builtin_amdgcn_mfma_f32_16x16x32_bf16(afx0, bg[1][0], acc1, 0, 0, 0);
      acc2 = __builtin_amdgcn_mfma_f32_16x16x32_bf16(afx0, bg[2][0], acc2, 0, 0, 0);
      acc3 = __builtin_amdgcn_mfma_f32_16x16x32_bf16(afx0, bg[3][0], acc3, 0, 0, 0);
      acc0 = __builtin_amdgcn_mfma_f32_16x16x32_bf16(afx1, bg[0][1], acc0, 0, 0, 0);
      acc1 = __builtin_amdgcn_mfma_f32_16x16x32_bf16(afx1, bg[1][1], acc1, 0, 0, 0);
      acc2 = __builtin_amdgcn_mfma_f32_16x16x32_bf16(afx1, bg[2][1], acc2, 0, 0, 0);
      acc3 = __builtin_amdgcn_mfma_f32_16x16x32_bf16(afx1, bg[3][1], acc3, 0, 0, 0);
      acc0 = __builtin_amdgcn_mfma_f32_16x16x32_bf16(afh0, bg[0][2], acc0, 0, 0, 0);
      acc1 = __builtin_amdgcn_mfma_f32_16x16x32_bf16(afh0, bg[1][2], acc1, 0, 0, 0);
      acc2 = __builtin_amdgcn_mfma_f32_16x16x32_bf16(afh0, bg[2][2], acc2, 0, 0, 0);
      acc3 = __builtin_amdgcn_mfma_f32_16x16x32_bf16(afh0, bg[3][2], acc3, 0, 0, 0);
      acc0 = __builtin_amdgcn_mfma_f32_16x16x32_bf16(afh1, bg[0][3], acc0, 0, 0, 0);
      acc1 = __builtin_amdgcn_mfma_f32_16x16x32_bf16(afh1, bg[1][3], acc1, 0, 0, 0);
      acc2 = __builtin_amdgcn_mfma_f32_16x16x32_bf16(afh1, bg[2][3], acc2, 0, 0, 0);
      acc3 = __builtin_amdgcn_mfma_f32_16x16x32_bf16(afh1, bg[3][3], acc3, 0, 0, 0);

      f32x4 mn = *(const f32x4*)(sm + MSK + (T + 1) * 64 + lg * 16);  // m(t+1), 4 rows
      #pragma unroll
      for (int q = 0; q < 4; ++q) {
        float iv = sigf(acc0[q]);
        float fv = sigf(acc1[q]);
        float gv = tanhfast(acc2[q]);
        float o  = sigf(acc3[q]);
        float c  = fv * creg[q] + iv * gv;
        float h  = o * tanhfast(c);
        hlast[q] = h;
        creg[q]  = c * mn[q];
        *(ushort*)(sm + HBWR + myHwr[q]) = f2bf(h * mn[q]);  // masked, for gates(t+1)
        *(ushort*)(sm + HMWR + myHwr[q]) = f2bf(h);          // unmasked, for MLP(t)
      }
    } else if (w == 4) {
      if (T > 0) do_mlp(T - 1, HMPREV);                      // deferred one step
    } else {
      if (oact) {
        if (T + 1 < SEQ) {                                   // commit obs(T+1)
          #pragma unroll
          for (int e = 0; e < 4; ++e)
            *(ushort*)(sm + XWR + a_obs[e]) = f2bf(ovh[e]);
        }
        if (T + 2 < SEQ)                                     // prefetch obs(T+2)
          ovh = *(const f32x4*)(obs + ((size_t)(T + 2) * BATCH + b0) * OBS + oidx * 4);
      }
    }
    __syncthreads();
  };

  for (int t = 0; t < SEQ; t += 2) {
    do_step(t,     XS0, XS1, HB0, HB1, HM1, HM0);
    do_step(t + 1, XS1, XS0, HB1, HB0, HM0, HM1);
  }
  if (w == 4) do_mlp(SEQ - 1, HM1);   // tail: means(63)

  // ---------------- final h, c ----------------
  if (w < 4) {
    float* hout = out + (size_t)SEQ * BATCH * ACT;
    float* cout = hout + (size_t)BATCH * HID;
    #pragma unroll
    for (int q = 0; q < 4; ++q) {
      int r = lg * 4 + q;
      hout[(size_t)(b0 + r) * HID + j] = hlast[q];  // h(63) unmasked
      cout[(size_t)(b0 + r) * HID + j] = creg[q];   // c(63) * m(64)=1
    }
  }
}

extern "C" void kernel_launch(void* const* d_in, const int* in_sizes, int n_in,
                              void* d_out, int out_size, void* d_ws, size_t ws_size,
                              hipStream_t stream) {
  (void)in_sizes; (void)n_in; (void)d_ws; (void)ws_size; (void)out_size;
  lstm_policy<<<dim3(NWG), dim3(NT), 0, stream>>>(
      (const float*)d_in[0], (const float*)d_in[1], (const float*)d_in[2],
      (const float*)d_in[3], (const float*)d_in[4], (const float*)d_in[5],
      (const float*)d_in[6], (const float*)d_in[7], (const float*)d_in[8],
      (const float*)d_in[9], (const float*)d_in[10], (const int*)d_in[11],
      (float*)d_out);
}

// Round 6
// 129.458 us; speedup vs baseline: 2.2269x; 1.1853x over previous
//
#include <hip/hip_runtime.h>
#include <hip/hip_bf16.h>

#define SEQ   64
#define BATCH 8192
#define OBS   47
#define HID   64
#define MLPH  32
#define ACT   12

#define BT 16            // batch rows per workgroup
#define NT 512           // 8 waves: 0-3 heavy (h-GEMM+cell), 4-7 light (x-GEMM; 4:+MLP, 5-7:+obs staging)
#define NWG (BATCH / BT) // 512 workgroups -> 2 per CU

// LDS layout (bytes)
#define XS0 0            // x(t even) [16][64] bf16 swz      2048
#define XS1 2048         // x(t odd)
#define HB0 4096         // masked h ping-pong [16][64] bf16 swz
#define HB1 6144
#define HM0 8192         // unmasked h ping-pong (for MLP)
#define HM1 10240
#define XA0 12288        // xacc ping-pong [p=256][row=16] bf16 swzX  8192 each
#define XA1 20480
#define M2O 28672        // wave-4 ELU scratch [16][32] bf16 swzM     1024
#define MSK 29696        // masks [65][16] f32                        4160
#define W1L 33856        // W1 frag table 4*64*16B                    4096
#define W2L 37952        // W2 frag table 64*16B                      1024
#define SMEM_BYTES 38976

typedef __attribute__((ext_vector_type(8))) short short8;
typedef __attribute__((ext_vector_type(4))) short short4v;
typedef __attribute__((ext_vector_type(4))) float f32x4;

__device__ __forceinline__ ushort f2bf(float f) {
  union { float f; unsigned u; } v; v.f = f;
  return (ushort)((v.u + 0x7FFFu + ((v.u >> 16) & 1u)) >> 16);
}
__device__ __forceinline__ float bf2f(ushort u) {
  union { float f; unsigned u; } v; v.u = (unsigned)u << 16; return v.f;
}
__device__ __forceinline__ float sigf(float x) { return 1.0f / (1.0f + __expf(-x)); }
__device__ __forceinline__ float tanhfast(float x) { return 1.0f - 2.0f / (1.0f + __expf(2.0f * x)); }

// XOR swizzles (bijective)
__device__ __forceinline__ int swz (int r, int ks) { return (r * 128 + ks * 2) ^ ((r & 7) << 4); }
__device__ __forceinline__ int swzM(int r, int cs) { return (r * 64  + cs * 2) ^ ((r & 7) << 4); }
// xacc: [p][rq] 8B slots; fold p's bit2-3 into the slot index to spread banks
__device__ __forceinline__ int swzX(int p, int rq) { return p * 32 + ((rq ^ ((p >> 2) & 3)) << 3); }

extern "C" __global__ void __launch_bounds__(NT, 4)
lstm_policy(const float* __restrict__ obs, const float* __restrict__ h0,
            const float* __restrict__ c0, const float* __restrict__ Wih,
            const float* __restrict__ Whh, const float* __restrict__ bih,
            const float* __restrict__ bhh, const float* __restrict__ W1,
            const float* __restrict__ b1, const float* __restrict__ W2,
            const float* __restrict__ b2, const int* __restrict__ masks,
            float* __restrict__ out)
{
  __shared__ __align__(16) char sm[SMEM_BYTES];
  const int tid  = threadIdx.x;
  const int b0   = blockIdx.x * BT;
  const int lane = tid & 63;
  const int w    = tid >> 6;          // 0..7
  const int lr   = lane & 15;
  const int lg   = lane >> 4;         // 0..3
  const int j    = (w & 3) * 16 + lr; // heavy: owned hidden unit; light: owned col-tile base

  // ---------------- phase 0: zeros + masks + MLP weight tables ----------------
  for (int idx = tid; idx < 256; idx += NT)          // zero XS0+XS1 (pads persist)
    *(f32x4*)(sm + idx * 16) = (f32x4){0.f, 0.f, 0.f, 0.f};
  for (int idx = tid; idx < SEQ * BT; idx += NT) {
    int t = idx >> 4, r = idx & 15;
    *(float*)(sm + MSK + idx * 4) = (float)masks[t * BATCH + b0 + r];
  }
  if (tid < BT) *(float*)(sm + MSK + (SEQ * BT + tid) * 4) = 1.0f;   // m(64)=1
  if (tid < 64) {   // MLP weight fragment tables
    int l = tid, llr = l & 15, llg = l >> 4;
    #pragma unroll
    for (int tt = 0; tt < 2; ++tt)
      #pragma unroll
      for (int kk = 0; kk < 2; ++kk) {
        short8 f;
        const float* src = W1 + (tt * 16 + llr) * HID + kk * 32 + llg * 8;
        #pragma unroll
        for (int e = 0; e < 8; ++e) f[e] = (short)f2bf(src[e]);
        *(short8*)(sm + W1L + ((tt * 2 + kk) * 64 + l) * 16) = f;
      }
    short8 f2;
    #pragma unroll
    for (int e = 0; e < 8; ++e)
      f2[e] = (llr < ACT) ? (short)f2bf(W2[llr * MLPH + llg * 8 + e]) : (short)0;
    *(short8*)(sm + W2L + l * 16) = f2;
  }
  __syncthreads();

  // ---------------- phase 1: per-class register builds + initial staging ----------------
  short8 wf[4][2];      // heavy: Whh frags ; light: Wih frags (built once, 32 VGPR)
  float biasg[4] = {0, 0, 0, 0};
  float creg[4] = {0, 0, 0, 0}, hlast[4] = {0, 0, 0, 0};
  int myHwr[4] = {0, 0, 0, 0};

  if (w < 4) {
    #pragma unroll
    for (int nf = 0; nf < 4; ++nf) {
      int n = nf * 64 + j;
      #pragma unroll
      for (int kk = 0; kk < 2; ++kk) {
        const float* src = Whh + n * HID + kk * 32 + lg * 8;
        short8 f;
        #pragma unroll
        for (int e = 0; e < 8; ++e) f[e] = (short)f2bf(src[e]);
        wf[nf][kk] = f;
      }
    }
    #pragma unroll
    for (int q = 0; q < 4; ++q) {
      int r = lg * 4 + q;
      myHwr[q] = swz(r, j);
      float m0 = *(const float*)(sm + MSK + r * 4);
      float hv = h0[(size_t)(b0 + r) * HID + j] * m0;
      creg[q]  = c0[(size_t)(b0 + r) * HID + j] * m0;
      *(ushort*)(sm + HB0 + myHwr[q]) = f2bf(hv);
    }
  } else {
    #pragma unroll
    for (int nf = 0; nf < 4; ++nf) {
      int n = nf * 64 + j;               // j = (w&3)*16+lr = this light wave's cols
      biasg[nf] = bih[n] + bhh[n];
      #pragma unroll
      for (int kk = 0; kk < 2; ++kk) {
        short8 f;
        #pragma unroll
        for (int e = 0; e < 8; ++e) {
          int k = kk * 32 + lg * 8 + e;
          f[e] = (k < OBS) ? (short)f2bf(Wih[n * OBS + k]) : (short)0;
        }
        wf[nf][kk] = f;
      }
    }
  }

  float b1v0 = 0.f, b1v1 = 0.f, b2v = 0.f;
  if (w == 4) { b1v0 = b1[lr]; b1v1 = b1[16 + lr]; b2v = (lr < ACT) ? b2[lr] : 0.f; }

  // obs staging: waves 5-7 (lanes 320..511), 188 slots of f32x4 cover 16*47 floats
  const int oidx = tid - 320;
  const bool oact = (w >= 5) && (oidx >= 0) && (oidx < 188);
  int a_obs[4] = {0, 0, 0, 0};
  f32x4 ovh = {0.f, 0.f, 0.f, 0.f};
  if (oact) {
    #pragma unroll
    for (int e = 0; e < 4; ++e) {
      int flat = oidx * 4 + e;
      int r = flat / OBS, k = flat - OBS * r;
      a_obs[e] = swz(r, k);
    }
    f32x4 v0 = *(const f32x4*)(obs + (size_t)b0 * OBS + oidx * 4);               // x(0)
    f32x4 v1 = *(const f32x4*)(obs + ((size_t)BATCH + b0) * OBS + oidx * 4);     // x(1)
    #pragma unroll
    for (int e = 0; e < 4; ++e) *(ushort*)(sm + XS0 + a_obs[e]) = f2bf(v0[e]);
    #pragma unroll
    for (int e = 0; e < 4; ++e) *(ushort*)(sm + XS1 + a_obs[e]) = f2bf(v1[e]);
    ovh = *(const f32x4*)(obs + ((size_t)2 * BATCH + b0) * OBS + oidx * 4);      // x(2)
  }
  __syncthreads();

  // ---------------- light x-GEMM body: xacc from XS buffer -> XA buffer ----------------
  // storage index p = (wave&3)*64 + nf*16 + lr  (slot rq = lg holds rows lg*4..lg*4+3)
  auto do_xgemm = [&](int XSRD, int XAWR) {
    short8 ax0 = *(const short8*)(sm + XSRD + swz(lr, lg * 8));
    short8 ax1 = *(const short8*)(sm + XSRD + swz(lr, 32 + lg * 8));
    #pragma unroll
    for (int nf = 0; nf < 4; ++nf) {
      f32x4 a = (f32x4){biasg[nf], biasg[nf], biasg[nf], biasg[nf]};
      a = __builtin_amdgcn_mfma_f32_16x16x32_bf16(ax0, wf[nf][0], a, 0, 0, 0);
      a = __builtin_amdgcn_mfma_f32_16x16x32_bf16(ax1, wf[nf][1], a, 0, 0, 0);
      short4v o;
      #pragma unroll
      for (int q = 0; q < 4; ++q) o[q] = (short)f2bf(a[q]);
      *(short4v*)(sm + XAWR + swzX((w & 3) * 64 + nf * 16 + lr, lg)) = o;
    }
  };

  // phase 2: xacc(0)
  if (w >= 4) do_xgemm(XS0, XA0);
  __syncthreads();

  // ---------------- MLP body (wave 4) ----------------
  auto do_mlp = [&](int TOUT, int HMP) {
    short8 hf0 = *(const short8*)(sm + HMP + swz(lr, lg * 8));
    short8 hf1 = *(const short8*)(sm + HMP + swz(lr, 32 + lg * 8));
    f32x4 am0 = (f32x4){b1v0, b1v0, b1v0, b1v0};
    f32x4 am1 = (f32x4){b1v1, b1v1, b1v1, b1v1};
    short8 wA;
    wA = *(const short8*)(sm + W1L + (0 * 64 + lane) * 16);
    am0 = __builtin_amdgcn_mfma_f32_16x16x32_bf16(hf0, wA, am0, 0, 0, 0);
    wA = *(const short8*)(sm + W1L + (1 * 64 + lane) * 16);
    am0 = __builtin_amdgcn_mfma_f32_16x16x32_bf16(hf1, wA, am0, 0, 0, 0);
    wA = *(const short8*)(sm + W1L + (2 * 64 + lane) * 16);
    am1 = __builtin_amdgcn_mfma_f32_16x16x32_bf16(hf0, wA, am1, 0, 0, 0);
    wA = *(const short8*)(sm + W1L + (3 * 64 + lane) * 16);
    am1 = __builtin_amdgcn_mfma_f32_16x16x32_bf16(hf1, wA, am1, 0, 0, 0);
    #pragma unroll
    for (int q = 0; q < 4; ++q) {
      int r = lg * 4 + q;
      float v0 = am0[q], v1 = am1[q];
      float e0 = v0 > 0.f ? v0 : (__expf(v0) - 1.f);
      float e1 = v1 > 0.f ? v1 : (__expf(v1) - 1.f);
      *(ushort*)(sm + M2O + swzM(r, lr))      = f2bf(e0);
      *(ushort*)(sm + M2O + swzM(r, 16 + lr)) = f2bf(e1);
    }
    f32x4 a2 = (f32x4){b2v, b2v, b2v, b2v};   // same-wave LDS RAW: in-order DS + lgkmcnt
    short8 ef  = *(const short8*)(sm + M2O + swzM(lr, lg * 8));
    short8 w2f = *(const short8*)(sm + W2L + lane * 16);
    a2 = __builtin_amdgcn_mfma_f32_16x16x32_bf16(ef, w2f, a2, 0, 0, 0);
    if (lr < ACT) {
      #pragma unroll
      for (int q = 0; q < 4; ++q)
        out[((size_t)TOUT * BATCH + b0 + lg * 4 + q) * ACT + lr] = a2[q];
    }
  };

  // ---------------- one step: ONE barrier ----------------
  // step T: heavy reads HB[T&1], XA[T&1]; writes HB[~], HM[T&1].
  //         light reads XS[(T+1)&1] -> writes XA[(T+1)&1]; stages x(T+2) into XS[T&1].
  //         wave4 additionally: MLP(T-1) from HM[(T+1)&1].
  auto do_step = [&](int T, int XSRD, int XSWR, int HBRD, int HBWR,
                     int HMPREV, int HMWR, int XARD, int XAWR) {
    if (w < 4) {
      short8 ah0 = *(const short8*)(sm + HBRD + swz(lr, lg * 8));
      short8 ah1 = *(const short8*)(sm + HBRD + swz(lr, 32 + lg * 8));
      f32x4 acc0, acc1, acc2, acc3;
      {
        // read storage index p = w*64 + nf*16 + lr (matches do_xgemm's write)
        short4v x0 = *(const short4v*)(sm + XARD + swzX(w * 64 +  0 + lr, lg));
        short4v x1 = *(const short4v*)(sm + XARD + swzX(w * 64 + 16 + lr, lg));
        short4v x2 = *(const short4v*)(sm + XARD + swzX(w * 64 + 32 + lr, lg));
        short4v x3 = *(const short4v*)(sm + XARD + swzX(w * 64 + 48 + lr, lg));
        acc0 = (f32x4){bf2f((ushort)x0[0]), bf2f((ushort)x0[1]), bf2f((ushort)x0[2]), bf2f((ushort)x0[3])};
        acc1 = (f32x4){bf2f((ushort)x1[0]), bf2f((ushort)x1[1]), bf2f((ushort)x1[2]), bf2f((ushort)x1[3])};
        acc2 = (f32x4){bf2f((ushort)x2[0]), bf2f((ushort)x2[1]), bf2f((ushort)x2[2]), bf2f((ushort)x2[3])};
        acc3 = (f32x4){bf2f((ushort)x3[0]), bf2f((ushort)x3[1]), bf2f((ushort)x3[2]), bf2f((ushort)x3[3])};
      }
      acc0 = __builtin_amdgcn_mfma_f32_16x16x32_bf16(ah0, wf[0][0], acc0, 0, 0, 0);
      acc1 = __builtin_amdgcn_mfma_f32_16x16x32_bf16(ah0, wf[1][0], acc1, 0, 0, 0);
      acc2 = __builtin_amdgcn_mfma_f32_16x16x32_bf16(ah0, wf[2][0], acc2, 0, 0, 0);
      acc3 = __builtin_amdgcn_mfma_f32_16x16x32_bf16(ah0, wf[3][0], acc3, 0, 0, 0);
      acc0 = __builtin_amdgcn_mfma_f32_16x16x32_bf16(ah1, wf[0][1], acc0, 0, 0, 0);
      acc1 = __builtin_amdgcn_mfma_f32_16x16x32_bf16(ah1, wf[1][1], acc1, 0, 0, 0);
      acc2 = __builtin_amdgcn_mfma_f32_16x16x32_bf16(ah1, wf[2][1], acc2, 0, 0, 0);
      acc3 = __builtin_amdgcn_mfma_f32_16x16x32_bf16(ah1, wf[3][1], acc3, 0, 0, 0);

      f32x4 mn = *(const f32x4*)(sm + MSK + (T + 1) * 64 + lg * 16);
      #pragma unroll
      for (int q = 0; q < 4; ++q) {
        float iv = sigf(acc0[q]);
        float fv = sigf(acc1[q]);
        float gv = tanhfast(acc2[q]);
        float o  = sigf(acc3[q]);
        float c  = fv * creg[q] + iv * gv;
        float h  = o * tanhfast(c);
        hlast[q] = h;
        creg[q]  = c * mn[q];
        *(ushort*)(sm + HBWR + myHwr[q]) = f2bf(h * mn[q]);
        *(ushort*)(sm + HMWR + myHwr[q]) = f2bf(h);
      }
    } else {
      if (T + 1 < SEQ) do_xgemm(XSRD, XAWR);
      if (w == 4) {
        if (T > 0) do_mlp(T - 1, HMPREV);
      } else if (oact) {
        f32x4 ovn = ovh;
        if (T + 3 < SEQ)
          ovn = *(const f32x4*)(obs + ((size_t)(T + 3) * BATCH + b0) * OBS + oidx * 4);
        if (T + 2 < SEQ) {
          #pragma unroll
          for (int e = 0; e < 4; ++e)
            *(ushort*)(sm + XSWR + a_obs[e]) = f2bf(ovh[e]);
        }
        ovh = ovn;
      }
    }
    __syncthreads();
  };

  for (int t = 0; t < SEQ; t += 2) {
    do_step(t,     XS1, XS0, HB0, HB1, HM1, HM0, XA0, XA1);
    do_step(t + 1, XS0, XS1, HB1, HB0, HM0, HM1, XA1, XA0);
  }
  if (w == 4) do_mlp(SEQ - 1, HM1);   // means(63)

  // ---------------- final h, c ----------------
  if (w < 4) {
    float* hout = out + (size_t)SEQ * BATCH * ACT;
    float* cout = hout + (size_t)BATCH * HID;
    #pragma unroll
    for (int q = 0; q < 4; ++q) {
      int r = lg * 4 + q;
      hout[(size_t)(b0 + r) * HID + j] = hlast[q];  // h(63) unmasked
      cout[(size_t)(b0 + r) * HID + j] = creg[q];   // c(63) * m(64)=1
    }
  }
}

extern "C" void kernel_launch(void* const* d_in, const int* in_sizes, int n_in,
                              void* d_out, int out_size, void* d_ws, size_t ws_size,
                              hipStream_t stream) {
  (void)in_sizes; (void)n_in; (void)d_ws; (void)ws_size; (void)out_size;
  lstm_policy<<<dim3(NWG), dim3(NT), 0, stream>>>(
      (const float*)d_in[0], (const float*)d_in[1], (const float*)d_in[2],
      (const float*)d_in[3], (const float*)d_in[4], (const float*)d_in[5],
      (const float*)d_in[6], (const float*)d_in[7], (const float*)d_in[8],
      (const float*)d_in[9], (const float*)d_in[10], (const int*)d_in[11],
      (float*)d_out);
}